// Round 1
// baseline (21353.099 us; speedup 1.0000x reference)
//
#include <hip/hip_runtime.h>
#include <hip/hip_bf16.h>
#include <math.h>

#define BB 128
#define TT 1024
#define DIN 64
#define HH 256
#define EE 32
#define G4 1024  // 4*H

// ---------- bf16 helpers (OCP bf16 = top 16 bits of fp32, RNE) ----------
__device__ __forceinline__ unsigned bf16rne(float f) {
  unsigned u = __float_as_uint(f);
  return (u + 0x7fffu + ((u >> 16) & 1u)) >> 16;
}
__device__ __forceinline__ float bf16round(float f) {
  return __uint_as_float(bf16rne(f) << 16);
}
__device__ __forceinline__ unsigned packbf(float a, float b) {
  return bf16rne(a) | (bf16rne(b) << 16);
}
__device__ __forceinline__ float blo(unsigned u) { return __uint_as_float(u << 16); }
__device__ __forceinline__ float bhi(unsigned u) { return __uint_as_float(u & 0xffff0000u); }
__device__ __forceinline__ float sigm(float x) { return 1.0f / (1.0f + expf(-x)); }

// ---------- prep: Wfold = W_proj @ W_ih, packed bf16 quads [dq][1024] ----------
__global__ void fold_kernel(const float* __restrict__ Wproj, const float* __restrict__ Wih,
                            uint2* __restrict__ Wfold_pk) {
  int idx = blockIdx.x * blockDim.x + threadIdx.x;
  if (idx >= 16 * 1024) return;
  int dq = idx >> 10, j = idx & 1023;
  float a0 = 0.f, a1 = 0.f, a2 = 0.f, a3 = 0.f;
  for (int k = 0; k < 256; ++k) {
    float wk = Wih[k * 1024 + j];
    a0 += Wproj[(4 * dq + 0) * 256 + k] * wk;
    a1 += Wproj[(4 * dq + 1) * 256 + k] * wk;
    a2 += Wproj[(4 * dq + 2) * 256 + k] * wk;
    a3 += Wproj[(4 * dq + 3) * 256 + k] * wk;
  }
  Wfold_pk[idx] = make_uint2(packbf(a0, a1), packbf(a2, a3));
}

// bfold[j] = b_proj @ W_ih + b_lstm   (fp32)
__global__ void bfold_kernel(const float* __restrict__ bproj, const float* __restrict__ Wih,
                             const float* __restrict__ blstm, float* __restrict__ bfold) {
  int j = blockIdx.x * blockDim.x + threadIdx.x;
  if (j >= 1024) return;
  float a = blstm[j];
  for (int k = 0; k < 256; ++k) a += bproj[k] * Wih[k * 1024 + j];
  bfold[j] = a;
}

// generic: src [K][N] fp32 -> dst [K/4][N] uint2 of packed bf16 (k, k+1 | k+2, k+3)
__global__ void pack_bf16_quad(const float* __restrict__ src, uint2* __restrict__ dst,
                               int K, int N) {
  int idx = blockIdx.x * blockDim.x + threadIdx.x;
  int total = (K >> 2) * N;
  if (idx >= total) return;
  int kq = idx / N, j = idx - kq * N;
  float a = src[(4 * kq + 0) * N + j];
  float b = src[(4 * kq + 1) * N + j];
  float c = src[(4 * kq + 2) * N + j];
  float d = src[(4 * kq + 3) * N + j];
  dst[idx] = make_uint2(packbf(a, b), packbf(c, d));
}

// ---------- output 2: first temporal difference, zero-padded at t=0 ----------
__global__ void d1_kernel(const float* __restrict__ x, float* __restrict__ out2) {
  int idx = blockIdx.x * blockDim.x + threadIdx.x;  // over B*T*(DIN/4) float4s
  const int per_t = DIN / 4;                        // 16
  if (idx >= BB * TT * per_t) return;
  int t = (idx / per_t) % TT;
  float4 cur = reinterpret_cast<const float4*>(x)[idx];
  float4 res;
  if (t == 0) {
    res = make_float4(0.f, 0.f, 0.f, 0.f);
  } else {
    float4 prv = reinterpret_cast<const float4*>(x)[idx - per_t];
    res = make_float4(cur.x - prv.x, cur.y - prv.y, cur.z - prv.z, cur.w - prv.w);
  }
  reinterpret_cast<float4*>(out2)[idx] = res;
}

// ---------- the sequential scan: one block per batch row ----------
__global__ __launch_bounds__(256) void scan_kernel(
    const float* __restrict__ x, const float* __restrict__ ev, const float* __restrict__ td,
    const uint2* __restrict__ Wfold, const float* __restrict__ bfold,
    const uint2* __restrict__ Whh, const uint2* __restrict__ Whg,
    const uint2* __restrict__ Wmk, const uint2* __restrict__ We,
    const float* __restrict__ bmk, const float* __restrict__ bhg, const float* __restrict__ be,
    const float* __restrict__ decay, float* __restrict__ features) {
  const int b = blockIdx.x;
  const int j = threadIdx.x;  // hidden column 0..255

  __shared__ float hs[HH];
  __shared__ float xs[DIN];
  __shared__ float es[EE];

  float c = 0.f;
  const float sp = log1pf(expf(decay[0]));

  const float b_i = bfold[j];
  const float b_f = bfold[256 + j];
  const float b_g = bfold[512 + j];
  const float b_o = bfold[768 + j];
  const float b_hgv = bhg[j];
  const float b_mkv = bmk[j];
  const float b_ev = be[j];

  hs[j] = 0.f;
  if (j < DIN) xs[j] = bf16round(x[(size_t)(b * TT) * DIN + j]);
  if (j >= 64 && j < 64 + EE) es[j - 64] = bf16round(ev[(size_t)(b * TT) * EE + (j - 64)]);
  __syncthreads();

  for (int t = 0; t < TT; ++t) {
    const float dt = td[b * TT + t];
    const float factor = expf(-sp * dt);

    float gi = b_i, gf = b_f, gg = b_g, go = b_o;
    float ghg = b_hgv, gmk = b_mkv, ge = b_ev;

    // x-dependent part: K=64 (folded proj for i/f/g/o, raw for mk)
#pragma unroll
    for (int dq = 0; dq < DIN / 4; ++dq) {
      const float4 xv = *reinterpret_cast<const float4*>(&xs[4 * dq]);
      const uint2 wi = Wfold[dq * G4 + j];
      const uint2 wf = Wfold[dq * G4 + 256 + j];
      const uint2 wg = Wfold[dq * G4 + 512 + j];
      const uint2 wo = Wfold[dq * G4 + 768 + j];
      const uint2 wm = Wmk[dq * HH + j];
      gi += xv.x * blo(wi.x) + xv.y * bhi(wi.x) + xv.z * blo(wi.y) + xv.w * bhi(wi.y);
      gf += xv.x * blo(wf.x) + xv.y * bhi(wf.x) + xv.z * blo(wf.y) + xv.w * bhi(wf.y);
      gg += xv.x * blo(wg.x) + xv.y * bhi(wg.x) + xv.z * blo(wg.y) + xv.w * bhi(wg.y);
      go += xv.x * blo(wo.x) + xv.y * bhi(wo.x) + xv.z * blo(wo.y) + xv.w * bhi(wo.y);
      gmk += xv.x * blo(wm.x) + xv.y * bhi(wm.x) + xv.z * blo(wm.y) + xv.w * bhi(wm.y);
    }

    // event part: K=32
#pragma unroll
    for (int eq = 0; eq < EE / 4; ++eq) {
      const float4 evv = *reinterpret_cast<const float4*>(&es[4 * eq]);
      const uint2 we_ = We[eq * HH + j];
      ge += evv.x * blo(we_.x) + evv.y * bhi(we_.x) + evv.z * blo(we_.y) + evv.w * bhi(we_.y);
    }

    // recurrent part: K=256 (i/f/g/o via W_hh, gate via W_hg)
#pragma unroll 8
    for (int kq = 0; kq < HH / 4; ++kq) {
      const float4 hv = *reinterpret_cast<const float4*>(&hs[4 * kq]);
      const uint2 wi = Whh[kq * G4 + j];
      const uint2 wf = Whh[kq * G4 + 256 + j];
      const uint2 wg = Whh[kq * G4 + 512 + j];
      const uint2 wo = Whh[kq * G4 + 768 + j];
      const uint2 wh = Whg[kq * HH + j];
      gi += hv.x * blo(wi.x) + hv.y * bhi(wi.x) + hv.z * blo(wi.y) + hv.w * bhi(wi.y);
      gf += hv.x * blo(wf.x) + hv.y * bhi(wf.x) + hv.z * blo(wf.y) + hv.w * bhi(wf.y);
      gg += hv.x * blo(wg.x) + hv.y * bhi(wg.x) + hv.z * blo(wg.y) + hv.w * bhi(wg.y);
      go += hv.x * blo(wo.x) + hv.y * bhi(wo.x) + hv.z * blo(wo.y) + hv.w * bhi(wo.y);
      ghg += hv.x * blo(wh.x) + hv.y * bhi(wh.x) + hv.z * blo(wh.y) + hv.w * bhi(wh.y);
    }

    // elementwise cell update
    const float is = sigm(gi), fs = sigm(gf), gt = tanhf(gg), os = sigm(go);
    const float gate = sigm(ghg);
    const float e_t = tanhf(ge);
    const float mks = sigm(gmk);
    const float impact = e_t * gate * factor;
    c = fs * c + is * gt + mks * tanhf(impact);
    const float hn = os * tanhf(c);

    features[((size_t)b * TT + t) * HH + j] = hn;

    __syncthreads();  // everyone done reading hs/xs/es of step t
    hs[j] = bf16round(hn);
    if (t + 1 < TT) {
      if (j < DIN) xs[j] = bf16round(x[((size_t)b * TT + t + 1) * DIN + j]);
      if (j >= 64 && j < 64 + EE) es[j - 64] = bf16round(ev[((size_t)b * TT + t + 1) * EE + (j - 64)]);
    }
    __syncthreads();
  }
}

// ---------- predictor MLP over all (b,t): gelu(h@W_p1+b_p1)@W_p2+b_p2 ----------
__global__ __launch_bounds__(256) void pred_kernel(
    const float* __restrict__ feat, const float* __restrict__ Wp1, const float* __restrict__ bp1,
    const float* __restrict__ Wp2, const float* __restrict__ bp2, float* __restrict__ out0) {
  int bt = blockIdx.x * blockDim.x + threadIdx.x;
  if (bt >= BB * TT) return;
  const float* hrow = feat + (size_t)bt * HH;
  float acc = bp2[0];
  for (int jt = 0; jt < 4; ++jt) {
    float mid[32];
#pragma unroll
    for (int jj = 0; jj < 32; ++jj) mid[jj] = bp1[jt * 32 + jj];
    for (int k = 0; k < HH; ++k) {
      const float hk = hrow[k];
      const float* wrow = Wp1 + k * 128 + jt * 32;
#pragma unroll
      for (int jj = 0; jj < 32; ++jj) mid[jj] += hk * wrow[jj];
    }
#pragma unroll
    for (int jj = 0; jj < 32; ++jj) {
      const float m = mid[jj];
      const float g = 0.5f * m * (1.0f + erff(m * 0.70710678118f));
      acc += g * Wp2[jt * 32 + jj];
    }
  }
  out0[bt] = acc;
}

extern "C" void kernel_launch(void* const* d_in, const int* in_sizes, int n_in,
                              void* d_out, int out_size, void* d_ws, size_t ws_size,
                              hipStream_t stream) {
  const float* x     = (const float*)d_in[0];
  const float* ev    = (const float*)d_in[1];
  const float* td    = (const float*)d_in[2];
  const float* Wproj = (const float*)d_in[3];
  const float* bproj = (const float*)d_in[4];
  const float* Wih   = (const float*)d_in[5];
  const float* Whh   = (const float*)d_in[6];
  const float* blstm = (const float*)d_in[7];
  const float* Wmk   = (const float*)d_in[8];
  const float* bmk   = (const float*)d_in[9];
  const float* We    = (const float*)d_in[10];
  const float* be    = (const float*)d_in[11];
  const float* Whg   = (const float*)d_in[12];
  const float* bhg   = (const float*)d_in[13];
  const float* decay = (const float*)d_in[14];
  const float* Wp1   = (const float*)d_in[15];
  const float* bp1   = (const float*)d_in[16];
  const float* Wp2   = (const float*)d_in[17];
  const float* bp2   = (const float*)d_in[18];

  float* out0 = (float*)d_out;                       // predictions [B,T,1]
  float* out1 = out0 + (size_t)BB * TT;              // features    [B,T,H]
  float* out2 = out1 + (size_t)BB * TT * HH;         // tmdo d1     [B,T,64]

  char* w = (char*)d_ws;
  uint2* Wfold_pk = (uint2*)w; w += (size_t)16 * 1024 * 8;
  uint2* Whh_pk   = (uint2*)w; w += (size_t)64 * 1024 * 8;
  uint2* Whg_pk   = (uint2*)w; w += (size_t)64 * 256 * 8;
  uint2* Wmk_pk   = (uint2*)w; w += (size_t)16 * 256 * 8;
  uint2* We_pk    = (uint2*)w; w += (size_t)8 * 256 * 8;
  float* bfold    = (float*)w; w += (size_t)1024 * 4;

  hipLaunchKernelGGL(fold_kernel, dim3(64), dim3(256), 0, stream, Wproj, Wih, Wfold_pk);
  hipLaunchKernelGGL(bfold_kernel, dim3(4), dim3(256), 0, stream, bproj, Wih, blstm, bfold);
  hipLaunchKernelGGL(pack_bf16_quad, dim3(256), dim3(256), 0, stream, Whh, Whh_pk, 256, 1024);
  hipLaunchKernelGGL(pack_bf16_quad, dim3(64), dim3(256), 0, stream, Whg, Whg_pk, 256, 256);
  hipLaunchKernelGGL(pack_bf16_quad, dim3(16), dim3(256), 0, stream, Wmk, Wmk_pk, 64, 256);
  hipLaunchKernelGGL(pack_bf16_quad, dim3(8), dim3(256), 0, stream, We, We_pk, 32, 256);

  hipLaunchKernelGGL(d1_kernel, dim3(8192), dim3(256), 0, stream, x, out2);

  hipLaunchKernelGGL(scan_kernel, dim3(BB), dim3(256), 0, stream,
                     x, ev, td, Wfold_pk, bfold, Whh_pk, Whg_pk, Wmk_pk, We_pk,
                     bmk, bhg, be, decay, out1);

  hipLaunchKernelGGL(pred_kernel, dim3((BB * TT) / 256), dim3(256), 0, stream,
                     out1, Wp1, bp1, Wp2, bp2, out0);
}

// Round 2
// 3150.696 us; speedup vs baseline: 6.7773x; 6.7773x over previous
//
#include <hip/hip_runtime.h>
#include <hip/hip_bf16.h>
#include <math.h>

#define BB 128
#define TT 1024
#define DIN 64
#define HH 256
#define EE 32
#define BT (BB * TT)

#ifndef USE_SDOT4
#define USE_SDOT4 1
#endif

typedef unsigned int uint;

__device__ __forceinline__ int dot4(uint a, uint b, int c) {
#if USE_SDOT4
  return __builtin_amdgcn_sdot4((int)a, (int)b, c, false);
#else
  int s = c;
  s += ((int)(a << 24) >> 24) * ((int)(b << 24) >> 24);
  s += ((int)(a << 16) >> 24) * ((int)(b << 16) >> 24);
  s += ((int)(a << 8) >> 24) * ((int)(b << 8) >> 24);
  s += ((int)a >> 24) * ((int)b >> 24);
  return s;
#endif
}

__device__ __forceinline__ float rcp_f(float x) { return __builtin_amdgcn_rcpf(x); }
__device__ __forceinline__ float sigm(float x) { return rcp_f(1.0f + __expf(-x)); }
__device__ __forceinline__ float tanh_f(float x) {
  return 1.0f - 2.0f * rcp_f(__expf(2.0f * x) + 1.0f);
}

// ---------- Wfold = W_proj @ W_ih (fp32, into ws) ----------
__global__ void fold_f32(const float* __restrict__ Wproj, const float* __restrict__ Wih,
                         float* __restrict__ Wfold) {
  int idx = blockIdx.x * blockDim.x + threadIdx.x;
  if (idx >= 64 * 1024) return;
  int d = idx >> 10, n = idx & 1023;
  float a = 0.f;
  for (int k = 0; k < 256; ++k) a += Wproj[d * 256 + k] * Wih[k * 1024 + n];
  Wfold[d * 1024 + n] = a;
}

// bfold[n] = b_proj @ W_ih + b_lstm
__global__ void bfold_kernel(const float* __restrict__ bproj, const float* __restrict__ Wih,
                             const float* __restrict__ blstm, float* __restrict__ bfold) {
  int n = blockIdx.x * blockDim.x + threadIdx.x;
  if (n >= 1024) return;
  float a = blstm[n];
  for (int k = 0; k < 256; ++k) a += bproj[k] * Wih[k * 1024 + n];
  bfold[n] = a;
}

// ---------- per-column int8 quantization: src [K][N] f32 -> dst [K/4][N] packed ----------
__global__ void quant_cols(const float* __restrict__ src, uint* __restrict__ dst,
                           float* __restrict__ scales, int K, int N) {
  int n = blockIdx.x * blockDim.x + threadIdx.x;
  if (n >= N) return;
  float m = 0.f;
  for (int k = 0; k < K; ++k) m = fmaxf(m, fabsf(src[k * N + n]));
  float mg = fmaxf(m, 1e-8f);
  scales[n] = mg * (1.0f / 127.0f);
  float inv = 127.0f / mg;
  for (int k4 = 0; k4 < (K >> 2); ++k4) {
    uint d = 0;
#pragma unroll
    for (int b = 0; b < 4; ++b) {
      int q = __float2int_rn(src[(k4 * 4 + b) * N + n] * inv);
      q = max(-127, min(127, q));
      d |= ((uint)(q & 0xff)) << (8 * b);
    }
    dst[k4 * N + n] = d;
  }
}

// ---------- per-(b,t) input quantization + decay factor (one wave per bt) ----------
__global__ __launch_bounds__(256) void prep_inputs(
    const float* __restrict__ x, const float* __restrict__ ev, const float* __restrict__ td,
    const float* __restrict__ decay, uint* __restrict__ xq, uint* __restrict__ eq,
    float* __restrict__ xsc, float* __restrict__ esc, float* __restrict__ fac) {
  int wid = threadIdx.x >> 6, lane = threadIdx.x & 63;
  int bt = blockIdx.x * 4 + wid;
  if (bt >= BT) return;
  float xv = x[(size_t)bt * DIN + lane];
  float evv = (lane < EE) ? ev[(size_t)bt * EE + lane] : 0.0f;
  float ax = fabsf(xv), ae = fabsf(evv);
#pragma unroll
  for (int m = 1; m < 64; m <<= 1) {
    ax = fmaxf(ax, __shfl_xor(ax, m));
    ae = fmaxf(ae, __shfl_xor(ae, m));
  }
  float mgx = fmaxf(ax, 1e-8f), mge = fmaxf(ae, 1e-8f);
  int qx = __float2int_rn(xv * (127.0f / mgx));
  qx = max(-127, min(127, qx));
  int qe = __float2int_rn(evv * (127.0f / mge));
  qe = max(-127, min(127, qe));
  uint dx = 0, de = 0;
#pragma unroll
  for (int b = 0; b < 4; ++b) dx |= ((uint)(__shfl(qx, lane * 4 + b) & 0xff)) << (8 * b);
#pragma unroll
  for (int b = 0; b < 4; ++b) de |= ((uint)(__shfl(qe, lane * 4 + b) & 0xff)) << (8 * b);
  if (lane < 16) xq[(size_t)bt * 16 + lane] = dx;
  if (lane < 8) eq[(size_t)bt * 8 + lane] = de;
  if (lane == 0) {
    xsc[bt] = mgx * (1.0f / 127.0f);
    esc[bt] = mge * (1.0f / 127.0f);
    float dv = decay[0];
    float sp = log1pf(__expf(dv));
    fac[bt] = __expf(-sp * td[bt]);
  }
}

// ---------- output 2: first temporal difference ----------
__global__ void d1_kernel(const float* __restrict__ x, float* __restrict__ out2) {
  int idx = blockIdx.x * blockDim.x + threadIdx.x;
  const int per_t = DIN / 4;
  if (idx >= BB * TT * per_t) return;
  int t = (idx / per_t) % TT;
  float4 cur = reinterpret_cast<const float4*>(x)[idx];
  float4 res;
  if (t == 0) {
    res = make_float4(0.f, 0.f, 0.f, 0.f);
  } else {
    float4 prv = reinterpret_cast<const float4*>(x)[idx - per_t];
    res = make_float4(cur.x - prv.x, cur.y - prv.y, cur.z - prv.z, cur.w - prv.w);
  }
  reinterpret_cast<float4*>(out2)[idx] = res;
}

// ---------- the scan: 1 block / batch row, 512 threads = (j in [0,256)) x (K-half) ----------
__global__ __launch_bounds__(512, 2) void scan_i8(
    const uint* __restrict__ Whhq, const float* __restrict__ sWhh,
    const uint* __restrict__ Wfoq, const float* __restrict__ sWfo,
    const uint* __restrict__ Whgq, const float* __restrict__ sWhg_s,
    const uint* __restrict__ Wmkq, const float* __restrict__ sWmk_s,
    const uint* __restrict__ Weq, const float* __restrict__ sWe_s,
    const float* __restrict__ bfold, const float* __restrict__ bhg,
    const float* __restrict__ bmk, const float* __restrict__ be,
    const uint* __restrict__ xq, const uint* __restrict__ eqp,
    const float* __restrict__ xsc, const float* __restrict__ esc,
    const float* __restrict__ fac, float* __restrict__ features) {
  const int b = blockIdx.x;
  const int tid = threadIdx.x;
  const int j = tid & 255;
  const int half = tid >> 8;

  __shared__ uint sWhg[64 * 256];   // 64 KB
  __shared__ uint sWmk[16 * 256];   // 16 KB
  __shared__ uint sWe[8 * 256];     //  8 KB
  __shared__ int part[11 * 256];    // 11 KB
  __shared__ __align__(16) uint hq[64];  // 256 B packed int8 h
  __shared__ float wmax[4];

  for (int i = tid; i < 64 * 256; i += 512) sWhg[i] = Whgq[i];
  for (int i = tid; i < 16 * 256; i += 512) sWmk[i] = Wmkq[i];
  for (int i = tid; i < 8 * 256; i += 512) sWe[i] = Weq[i];
  if (tid < 64) hq[tid] = 0;

  // register-resident weights (this thread's K-half, all 4 gates)
  uint whh[4][32];
#pragma unroll
  for (int g = 0; g < 4; ++g)
#pragma unroll
    for (int kk = 0; kk < 32; ++kk)
      whh[g][kk] = Whhq[(size_t)(half * 32 + kk) * 1024 + g * 256 + j];
  uint wfo[4][8];
#pragma unroll
  for (int g = 0; g < 4; ++g)
#pragma unroll
    for (int kk = 0; kk < 8; ++kk)
      wfo[g][kk] = Wfoq[(size_t)(half * 8 + kk) * 1024 + g * 256 + j];

  float s_hh[4], s_xf[4], bf4[4];
#pragma unroll
  for (int g = 0; g < 4; ++g) {
    s_hh[g] = sWhh[g * 256 + j];
    s_xf[g] = sWfo[g * 256 + j];
    bf4[g] = bfold[g * 256 + j];
  }
  const float s_hgv = sWhg_s[j], s_mkv = sWmk_s[j], s_ev = sWe_s[j];
  const float bhgv = bhg[j], bmkv = bmk[j], bev = be[j];

  float c = 0.0f, hscale = 1.0f;
  __syncthreads();

  for (int t = 0; t < TT; ++t) {
    const int bt = b * TT + t;
    const uint4* xq4 = (const uint4*)(xq + (size_t)bt * 16);
    const uint4 X0 = xq4[half * 2], X1 = xq4[half * 2 + 1];
    const uint4 E0 = ((const uint4*)(eqp + (size_t)bt * 8))[half];

    int ahh0 = 0, ahh1 = 0, ahh2 = 0, ahh3 = 0, ahg = 0;
    const uint4* h4 = (const uint4*)hq;
    const int whg_base = (half * 32) * 256 + j;
#pragma unroll
    for (int q4 = 0; q4 < 8; ++q4) {
      const uint4 hv = h4[half * 8 + q4];
      ahh0 = dot4(whh[0][q4 * 4 + 0], hv.x, ahh0);
      ahh0 = dot4(whh[0][q4 * 4 + 1], hv.y, ahh0);
      ahh0 = dot4(whh[0][q4 * 4 + 2], hv.z, ahh0);
      ahh0 = dot4(whh[0][q4 * 4 + 3], hv.w, ahh0);
      ahh1 = dot4(whh[1][q4 * 4 + 0], hv.x, ahh1);
      ahh1 = dot4(whh[1][q4 * 4 + 1], hv.y, ahh1);
      ahh1 = dot4(whh[1][q4 * 4 + 2], hv.z, ahh1);
      ahh1 = dot4(whh[1][q4 * 4 + 3], hv.w, ahh1);
      ahh2 = dot4(whh[2][q4 * 4 + 0], hv.x, ahh2);
      ahh2 = dot4(whh[2][q4 * 4 + 1], hv.y, ahh2);
      ahh2 = dot4(whh[2][q4 * 4 + 2], hv.z, ahh2);
      ahh2 = dot4(whh[2][q4 * 4 + 3], hv.w, ahh2);
      ahh3 = dot4(whh[3][q4 * 4 + 0], hv.x, ahh3);
      ahh3 = dot4(whh[3][q4 * 4 + 1], hv.y, ahh3);
      ahh3 = dot4(whh[3][q4 * 4 + 2], hv.z, ahh3);
      ahh3 = dot4(whh[3][q4 * 4 + 3], hv.w, ahh3);
      ahg = dot4(sWhg[whg_base + (q4 * 4 + 0) * 256], hv.x, ahg);
      ahg = dot4(sWhg[whg_base + (q4 * 4 + 1) * 256], hv.y, ahg);
      ahg = dot4(sWhg[whg_base + (q4 * 4 + 2) * 256], hv.z, ahg);
      ahg = dot4(sWhg[whg_base + (q4 * 4 + 3) * 256], hv.w, ahg);
    }

    int axf0 = 0, axf1 = 0, axf2 = 0, axf3 = 0, amk = 0, ae = 0;
    const uint xr[8] = {X0.x, X0.y, X0.z, X0.w, X1.x, X1.y, X1.z, X1.w};
    const int wmk_base = (half * 8) * 256 + j;
#pragma unroll
    for (int kk = 0; kk < 8; ++kk) {
      axf0 = dot4(wfo[0][kk], xr[kk], axf0);
      axf1 = dot4(wfo[1][kk], xr[kk], axf1);
      axf2 = dot4(wfo[2][kk], xr[kk], axf2);
      axf3 = dot4(wfo[3][kk], xr[kk], axf3);
      amk = dot4(sWmk[wmk_base + kk * 256], xr[kk], amk);
    }
    const uint er[4] = {E0.x, E0.y, E0.z, E0.w};
    const int we_base = (half * 4) * 256 + j;
#pragma unroll
    for (int kk = 0; kk < 4; ++kk) ae = dot4(sWe[we_base + kk * 256], er[kk], ae);

    if (half == 1) {
      part[0 * 256 + j] = ahh0;
      part[1 * 256 + j] = ahh1;
      part[2 * 256 + j] = ahh2;
      part[3 * 256 + j] = ahh3;
      part[4 * 256 + j] = axf0;
      part[5 * 256 + j] = axf1;
      part[6 * 256 + j] = axf2;
      part[7 * 256 + j] = axf3;
      part[8 * 256 + j] = ahg;
      part[9 * 256 + j] = amk;
      part[10 * 256 + j] = ae;
    }
    __syncthreads();  // B1: partials visible

    float hnew = 0.0f;
    if (half == 0) {
      const float xs = xsc[bt], es = esc[bt], fc = fac[bt];
      const int thh[4] = {ahh0 + part[0 * 256 + j], ahh1 + part[1 * 256 + j],
                          ahh2 + part[2 * 256 + j], ahh3 + part[3 * 256 + j]};
      const int txf[4] = {axf0 + part[4 * 256 + j], axf1 + part[5 * 256 + j],
                          axf2 + part[6 * 256 + j], axf3 + part[7 * 256 + j]};
      float pre[4];
#pragma unroll
      for (int g = 0; g < 4; ++g)
        pre[g] = (float)thh[g] * s_hh[g] * hscale + (float)txf[g] * s_xf[g] * xs + bf4[g];
      const float ghg = (float)(ahg + part[8 * 256 + j]) * s_hgv * hscale + bhgv;
      const float gmk = (float)(amk + part[9 * 256 + j]) * s_mkv * xs + bmkv;
      const float ge = (float)(ae + part[10 * 256 + j]) * s_ev * es + bev;
      const float et = tanh_f(ge), gate = sigm(ghg);
      const float impact = et * gate * fc;
      c = sigm(pre[1]) * c + sigm(pre[0]) * tanh_f(pre[2]) + sigm(gmk) * tanh_f(impact);
      hnew = sigm(pre[3]) * tanh_f(c);
      features[(size_t)bt * HH + j] = hnew;
      float m = fabsf(hnew);
#pragma unroll
      for (int d = 1; d < 64; d <<= 1) m = fmaxf(m, __shfl_xor(m, d));
      if ((tid & 63) == 0) wmax[tid >> 6] = m;
    }
    __syncthreads();  // B2: wave maxes visible

    const float hmax = fmaxf(fmaxf(wmax[0], wmax[1]), fmaxf(wmax[2], wmax[3]));
    const float mgh = fmaxf(hmax, 1e-6f);
    if (half == 0) {
      int q = __float2int_rn(hnew * (127.0f / mgh));
      q = max(-127, min(127, q));
      reinterpret_cast<unsigned char*>(hq)[j] = (unsigned char)(q & 0xff);
    }
    __syncthreads();  // B3: hq ready for next step
    hscale = mgh * (1.0f / 127.0f);
  }
}

// ---------- predictor MLP ----------
__global__ __launch_bounds__(256) void pred_kernel(
    const float* __restrict__ feat, const float* __restrict__ Wp1, const float* __restrict__ bp1,
    const float* __restrict__ Wp2, const float* __restrict__ bp2, float* __restrict__ out0) {
  int bt = blockIdx.x * blockDim.x + threadIdx.x;
  if (bt >= BB * TT) return;
  const float* hrow = feat + (size_t)bt * HH;
  float acc = bp2[0];
  for (int jt = 0; jt < 4; ++jt) {
    float mid[32];
#pragma unroll
    for (int jj = 0; jj < 32; ++jj) mid[jj] = bp1[jt * 32 + jj];
    for (int k = 0; k < HH; ++k) {
      const float hk = hrow[k];
      const float* wrow = Wp1 + k * 128 + jt * 32;
#pragma unroll
      for (int jj = 0; jj < 32; ++jj) mid[jj] += hk * wrow[jj];
    }
#pragma unroll
    for (int jj = 0; jj < 32; ++jj) {
      const float m = mid[jj];
      const float g = 0.5f * m * (1.0f + erff(m * 0.70710678118f));
      acc += g * Wp2[jt * 32 + jj];
    }
  }
  out0[bt] = acc;
}

extern "C" void kernel_launch(void* const* d_in, const int* in_sizes, int n_in,
                              void* d_out, int out_size, void* d_ws, size_t ws_size,
                              hipStream_t stream) {
  const float* x = (const float*)d_in[0];
  const float* ev = (const float*)d_in[1];
  const float* td = (const float*)d_in[2];
  const float* Wproj = (const float*)d_in[3];
  const float* bproj = (const float*)d_in[4];
  const float* Wih = (const float*)d_in[5];
  const float* Whh = (const float*)d_in[6];
  const float* blstm = (const float*)d_in[7];
  const float* Wmk = (const float*)d_in[8];
  const float* bmk = (const float*)d_in[9];
  const float* We = (const float*)d_in[10];
  const float* be = (const float*)d_in[11];
  const float* Whg = (const float*)d_in[12];
  const float* bhg = (const float*)d_in[13];
  const float* decay = (const float*)d_in[14];
  const float* Wp1 = (const float*)d_in[15];
  const float* bp1 = (const float*)d_in[16];
  const float* Wp2 = (const float*)d_in[17];
  const float* bp2 = (const float*)d_in[18];

  float* out0 = (float*)d_out;                  // predictions [B,T,1]
  float* out1 = out0 + (size_t)BB * TT;         // features    [B,T,H]
  float* out2 = out1 + (size_t)BB * TT * HH;    // tmdo d1     [B,T,64]

  char* w = (char*)d_ws;
  float* Wfold_f = (float*)w; w += (size_t)64 * 1024 * 4;       // 256 KB
  uint* Whhq = (uint*)w; w += (size_t)64 * 1024 * 4;            // 256 KB
  uint* Wfoq = (uint*)w; w += (size_t)16 * 1024 * 4;            // 64 KB
  uint* Whgq = (uint*)w; w += (size_t)64 * 256 * 4;             // 64 KB
  uint* Wmkq = (uint*)w; w += (size_t)16 * 256 * 4;             // 16 KB
  uint* Weq = (uint*)w; w += (size_t)8 * 256 * 4;               // 8 KB
  float* sWhh = (float*)w; w += 1024 * 4;
  float* sWfo = (float*)w; w += 1024 * 4;
  float* sWhg = (float*)w; w += 256 * 4;
  float* sWmk = (float*)w; w += 256 * 4;
  float* sWe = (float*)w; w += 256 * 4;
  float* bfold = (float*)w; w += 1024 * 4;
  uint* xq = (uint*)w; w += (size_t)BT * 16 * 4;                // 8 MB
  uint* eq = (uint*)w; w += (size_t)BT * 8 * 4;                 // 4 MB
  float* xsc = (float*)w; w += (size_t)BT * 4;
  float* esc = (float*)w; w += (size_t)BT * 4;
  float* fac = (float*)w; w += (size_t)BT * 4;

  hipLaunchKernelGGL(fold_f32, dim3(256), dim3(256), 0, stream, Wproj, Wih, Wfold_f);
  hipLaunchKernelGGL(bfold_kernel, dim3(4), dim3(256), 0, stream, bproj, Wih, blstm, bfold);
  hipLaunchKernelGGL(quant_cols, dim3(4), dim3(256), 0, stream, Whh, Whhq, sWhh, 256, 1024);
  hipLaunchKernelGGL(quant_cols, dim3(4), dim3(256), 0, stream, Wfold_f, Wfoq, sWfo, 64, 1024);
  hipLaunchKernelGGL(quant_cols, dim3(1), dim3(256), 0, stream, Whg, Whgq, sWhg, 256, 256);
  hipLaunchKernelGGL(quant_cols, dim3(1), dim3(256), 0, stream, Wmk, Wmkq, sWmk, 64, 256);
  hipLaunchKernelGGL(quant_cols, dim3(1), dim3(256), 0, stream, We, Weq, sWe, 32, 256);
  hipLaunchKernelGGL(prep_inputs, dim3(BT / 4), dim3(256), 0, stream,
                     x, ev, td, decay, xq, eq, xsc, esc, fac);
  hipLaunchKernelGGL(d1_kernel, dim3(8192), dim3(256), 0, stream, x, out2);

  hipLaunchKernelGGL(scan_i8, dim3(BB), dim3(512), 0, stream,
                     Whhq, sWhh, Wfoq, sWfo, Whgq, sWhg, Wmkq, sWmk, Weq, sWe,
                     bfold, bhg, bmk, be, xq, eq, xsc, esc, fac, out1);

  hipLaunchKernelGGL(pred_kernel, dim3(BT / 256), dim3(256), 0, stream,
                     out1, Wp1, bp1, Wp2, bp2, out0);
}

// Round 3
// 2646.185 us; speedup vs baseline: 8.0694x; 1.1907x over previous
//
#include <hip/hip_runtime.h>
#include <hip/hip_bf16.h>
#include <math.h>

#define BB 128
#define TT 1024
#define DIN 64
#define HH 256
#define EE 32
#define BT (BB * TT)

#ifndef USE_SDOT4
#define USE_SDOT4 1
#endif

typedef unsigned int uint;

__device__ __forceinline__ int dot4(uint a, uint b, int c) {
#if USE_SDOT4
  return __builtin_amdgcn_sdot4((int)a, (int)b, c, false);
#else
  int s = c;
  s += ((int)(a << 24) >> 24) * ((int)(b << 24) >> 24);
  s += ((int)(a << 16) >> 24) * ((int)(b << 16) >> 24);
  s += ((int)(a << 8) >> 24) * ((int)(b << 8) >> 24);
  s += ((int)a >> 24) * ((int)b >> 24);
  return s;
#endif
}

__device__ __forceinline__ float rcp_f(float x) { return __builtin_amdgcn_rcpf(x); }
__device__ __forceinline__ float sigm(float x) { return rcp_f(1.0f + __expf(-x)); }
__device__ __forceinline__ float tanh_f(float x) {
  return 1.0f - 2.0f * rcp_f(__expf(2.0f * x) + 1.0f);
}

// ---------- Wfold = W_proj @ W_ih (fp32) ----------
__global__ void fold_f32(const float* __restrict__ Wproj, const float* __restrict__ Wih,
                         float* __restrict__ Wfold) {
  int idx = blockIdx.x * blockDim.x + threadIdx.x;
  if (idx >= 64 * 1024) return;
  int d = idx >> 10, n = idx & 1023;
  float a = 0.f;
  for (int k = 0; k < 256; ++k) a += Wproj[d * 256 + k] * Wih[k * 1024 + n];
  Wfold[d * 1024 + n] = a;
}

// bfold[n] = b_proj @ W_ih + b_lstm
__global__ void bfold_kernel(const float* __restrict__ bproj, const float* __restrict__ Wih,
                             const float* __restrict__ blstm, float* __restrict__ bfold) {
  int n = blockIdx.x * blockDim.x + threadIdx.x;
  if (n >= 1024) return;
  float a = blstm[n];
  for (int k = 0; k < 256; ++k) a += bproj[k] * Wih[k * 1024 + n];
  bfold[n] = a;
}

// ---------- quantize h-side weights: cols 0..1023 = Whh(ifgo), 1024..1279 = Whg ----------
// output COL-major: dst[col*64 + k4]; scale folds the fixed h-scale 1/127.
__global__ void quant_h5(const float* __restrict__ Whh, const float* __restrict__ Whg,
                         uint* __restrict__ dst, float* __restrict__ sc) {
  int col = blockIdx.x * blockDim.x + threadIdx.x;
  if (col >= 1280) return;
  float m = 0.f;
  for (int k = 0; k < 256; ++k) {
    float v = (col < 1024) ? Whh[k * 1024 + col] : Whg[k * 256 + (col - 1024)];
    m = fmaxf(m, fabsf(v));
  }
  float mg = fmaxf(m, 1e-8f);
  sc[col] = mg * (1.0f / (127.0f * 127.0f));
  float inv = 127.0f / mg;
  for (int k4 = 0; k4 < 64; ++k4) {
    uint d = 0;
#pragma unroll
    for (int b = 0; b < 4; ++b) {
      int k = k4 * 4 + b;
      float v = (col < 1024) ? Whh[k * 1024 + col] : Whg[k * 256 + (col - 1024)];
      int q = __float2int_rn(v * inv);
      q = max(-127, min(127, q));
      d |= ((uint)(q & 0xff)) << (8 * b);
    }
    dst[col * 64 + k4] = d;
  }
}

// ---------- quantize x-side: cols 0..1023 = Wfold(ifgo), 1024..1279 = Wmk (K=64) ----------
__global__ void quant_x(const float* __restrict__ Wfold, const float* __restrict__ Wmk,
                        uint* __restrict__ dst, float* __restrict__ sc) {
  int col = blockIdx.x * blockDim.x + threadIdx.x;
  if (col >= 1280) return;
  float m = 0.f;
  for (int k = 0; k < 64; ++k) {
    float v = (col < 1024) ? Wfold[k * 1024 + col] : Wmk[k * 256 + (col - 1024)];
    m = fmaxf(m, fabsf(v));
  }
  float mg = fmaxf(m, 1e-8f);
  sc[col] = mg * (1.0f / 127.0f);
  float inv = 127.0f / mg;
  for (int k4 = 0; k4 < 16; ++k4) {
    uint d = 0;
#pragma unroll
    for (int b = 0; b < 4; ++b) {
      int k = k4 * 4 + b;
      float v = (col < 1024) ? Wfold[k * 1024 + col] : Wmk[k * 256 + (col - 1024)];
      int q = __float2int_rn(v * inv);
      q = max(-127, min(127, q));
      d |= ((uint)(q & 0xff)) << (8 * b);
    }
    dst[col * 16 + k4] = d;
  }
}

// ---------- quantize event weights: We [32][256], col-major out [col*8+k4] ----------
__global__ void quant_e(const float* __restrict__ We, uint* __restrict__ dst,
                        float* __restrict__ sc) {
  int col = blockIdx.x * blockDim.x + threadIdx.x;
  if (col >= 256) return;
  float m = 0.f;
  for (int k = 0; k < 32; ++k) m = fmaxf(m, fabsf(We[k * 256 + col]));
  float mg = fmaxf(m, 1e-8f);
  sc[col] = mg * (1.0f / 127.0f);
  float inv = 127.0f / mg;
  for (int k4 = 0; k4 < 8; ++k4) {
    uint d = 0;
#pragma unroll
    for (int b = 0; b < 4; ++b) {
      int q = __float2int_rn(We[(k4 * 4 + b) * 256 + col] * inv);
      q = max(-127, min(127, q));
      d |= ((uint)(q & 0xff)) << (8 * b);
    }
    dst[col * 8 + k4] = d;
  }
}

// ---------- per-(b,t) input quantization + scl={xsc,esc,fac,0} ----------
__global__ __launch_bounds__(256) void prep_inputs(
    const float* __restrict__ x, const float* __restrict__ ev, const float* __restrict__ td,
    const float* __restrict__ decay, uint* __restrict__ xq, uint* __restrict__ eq,
    float4* __restrict__ scl) {
  int wid = threadIdx.x >> 6, lane = threadIdx.x & 63;
  int bt = blockIdx.x * 4 + wid;
  if (bt >= BT) return;
  float xv = x[(size_t)bt * DIN + lane];
  float evv = (lane < EE) ? ev[(size_t)bt * EE + lane] : 0.0f;
  float ax = fabsf(xv), ae = fabsf(evv);
#pragma unroll
  for (int m = 1; m < 64; m <<= 1) {
    ax = fmaxf(ax, __shfl_xor(ax, m));
    ae = fmaxf(ae, __shfl_xor(ae, m));
  }
  float mgx = fmaxf(ax, 1e-8f), mge = fmaxf(ae, 1e-8f);
  int qx = __float2int_rn(xv * (127.0f / mgx));
  qx = max(-127, min(127, qx));
  int qe = __float2int_rn(evv * (127.0f / mge));
  qe = max(-127, min(127, qe));
  uint dx = 0, de = 0;
#pragma unroll
  for (int b = 0; b < 4; ++b) dx |= ((uint)(__shfl(qx, lane * 4 + b) & 0xff)) << (8 * b);
#pragma unroll
  for (int b = 0; b < 4; ++b) de |= ((uint)(__shfl(qe, lane * 4 + b) & 0xff)) << (8 * b);
  if (lane < 16) xq[(size_t)bt * 16 + lane] = dx;
  if (lane < 8) eq[(size_t)bt * 8 + lane] = de;
  if (lane == 0) {
    float sp = log1pf(__expf(decay[0]));
    scl[bt] = make_float4(mgx * (1.0f / 127.0f), mge * (1.0f / 127.0f),
                          __expf(-sp * td[bt]), 0.0f);
  }
}

// ---------- output 2: first temporal difference ----------
__global__ void d1_kernel(const float* __restrict__ x, float* __restrict__ out2) {
  int idx = blockIdx.x * blockDim.x + threadIdx.x;
  const int per_t = DIN / 4;
  if (idx >= BB * TT * per_t) return;
  int t = (idx / per_t) % TT;
  float4 cur = reinterpret_cast<const float4*>(x)[idx];
  float4 res;
  if (t == 0) {
    res = make_float4(0.f, 0.f, 0.f, 0.f);
  } else {
    float4 prv = reinterpret_cast<const float4*>(x)[idx - per_t];
    res = make_float4(cur.x - prv.x, cur.y - prv.y, cur.z - prv.z, cur.w - prv.w);
  }
  reinterpret_cast<float4*>(out2)[idx] = res;
}

// ---------- the scan: 1 block/row, 512 threads; lane pair (2i,2i+1) shares j, splits K ----------
__attribute__((amdgpu_waves_per_eu(2, 2)))
__global__ __launch_bounds__(512) void scan_i8(
    const uint* __restrict__ Whh5q, const float* __restrict__ schE,
    const uint* __restrict__ Xq, const float* __restrict__ sxj,
    const uint* __restrict__ Eq, const float* __restrict__ sej,
    const float* __restrict__ bfold, const float* __restrict__ bhg,
    const float* __restrict__ bmk, const float* __restrict__ be,
    const uint* __restrict__ xq, const uint* __restrict__ eqp,
    const float4* __restrict__ scl, float* __restrict__ feat) {
  const int b = blockIdx.x, tid = threadIdx.x;
  const int lane = tid & 63, w = tid >> 6;
  const int j = w * 32 + (lane >> 1);
  const int half = lane & 1;

  __shared__ __align__(16) uint XwL[1280 * 16];        // 80 KB
  __shared__ __align__(16) uint EwL[256 * 8];          //  8 KB
  __shared__ __align__(16) unsigned char hqB[2][256];  // double-buffered int8 h

  {
    const uint4* s4 = (const uint4*)Xq;
    uint4* d4 = (uint4*)XwL;
    for (int i = tid; i < 1280 * 4; i += 512) d4[i] = s4[i];
    const uint4* e4 = (const uint4*)Eq;
    uint4* de4 = (uint4*)EwL;
    if (tid < 512) de4[tid] = e4[tid];
    if (tid < 64) ((uint*)hqB)[tid] = 0;  // h_init = 0 in buffer 0
  }

  // h-side weights: 5 gates x 8 uint4 (this thread's K-half), kept in VGPRs
  uint4 wh[5][8];
#pragma unroll
  for (int g = 0; g < 5; ++g) {
    const uint4* src = (const uint4*)(Whh5q + (size_t)(g * 256 + j) * 64 + half * 32);
#pragma unroll
    for (int q = 0; q < 8; ++q) wh[g][q] = src[q];
  }

  float shE[5], sxE[5];
#pragma unroll
  for (int g = 0; g < 4; ++g) {
    shE[g] = schE[g * 256 + j];
    sxE[g] = sxj[g * 256 + j];
  }
  shE[4] = schE[1024 + j];
  sxE[4] = sxj[1024 + j];
  const float seE = sej[j];
  const float bf0 = bfold[j], bf1 = bfold[256 + j], bf2 = bfold[512 + j], bf3 = bfold[768 + j];
  const float bhgv = bhg[j], bmkv = bmk[j], bev = be[j];

  float c = 0.0f;
  int buf = 0;
  const uint4* xq4 = (const uint4*)xq;
  const uint4* eq4 = (const uint4*)eqp;
  __syncthreads();

  for (int t = 0; t < TT; ++t) {
    const int bt = b * TT + t;
    // per-step inputs: issued first, consumed after the h-dot phase (latency hidden)
    const uint4 X0 = xq4[bt * 4 + half * 2];
    const uint4 X1 = xq4[bt * 4 + half * 2 + 1];
    const uint4 E0 = eq4[bt * 2 + half];
    const float4 sv = scl[bt];

    // h-part: 5 gates x K=128 (this half)
    int ah0 = 0, ah1 = 0, ah2 = 0, ah3 = 0, ah4 = 0;
    const uint4* hp = (const uint4*)(&hqB[buf][half * 128]);
#pragma unroll
    for (int q = 0; q < 8; ++q) {
      const uint4 hv = hp[q];
      ah0 = dot4(wh[0][q].x, hv.x, ah0); ah0 = dot4(wh[0][q].y, hv.y, ah0);
      ah0 = dot4(wh[0][q].z, hv.z, ah0); ah0 = dot4(wh[0][q].w, hv.w, ah0);
      ah1 = dot4(wh[1][q].x, hv.x, ah1); ah1 = dot4(wh[1][q].y, hv.y, ah1);
      ah1 = dot4(wh[1][q].z, hv.z, ah1); ah1 = dot4(wh[1][q].w, hv.w, ah1);
      ah2 = dot4(wh[2][q].x, hv.x, ah2); ah2 = dot4(wh[2][q].y, hv.y, ah2);
      ah2 = dot4(wh[2][q].z, hv.z, ah2); ah2 = dot4(wh[2][q].w, hv.w, ah2);
      ah3 = dot4(wh[3][q].x, hv.x, ah3); ah3 = dot4(wh[3][q].y, hv.y, ah3);
      ah3 = dot4(wh[3][q].z, hv.z, ah3); ah3 = dot4(wh[3][q].w, hv.w, ah3);
      ah4 = dot4(wh[4][q].x, hv.x, ah4); ah4 = dot4(wh[4][q].y, hv.y, ah4);
      ah4 = dot4(wh[4][q].z, hv.z, ah4); ah4 = dot4(wh[4][q].w, hv.w, ah4);
    }

    // x-part: 5 gates x K=32 (this half) from LDS (col-major, b128 reads)
    int ax[5];
#pragma unroll
    for (int g = 0; g < 5; ++g) {
      const uint4 x0 = ((const uint4*)XwL)[(g * 256 + j) * 4 + half * 2];
      const uint4 x1 = ((const uint4*)XwL)[(g * 256 + j) * 4 + half * 2 + 1];
      int a = 0;
      a = dot4(x0.x, X0.x, a); a = dot4(x0.y, X0.y, a);
      a = dot4(x0.z, X0.z, a); a = dot4(x0.w, X0.w, a);
      a = dot4(x1.x, X1.x, a); a = dot4(x1.y, X1.y, a);
      a = dot4(x1.z, X1.z, a); a = dot4(x1.w, X1.w, a);
      ax[g] = a;
    }
    // e-part: K=16 (this half)
    const uint4 ew = ((const uint4*)EwL)[j * 2 + half];
    int aev = 0;
    aev = dot4(ew.x, E0.x, aev); aev = dot4(ew.y, E0.y, aev);
    aev = dot4(ew.z, E0.z, aev); aev = dot4(ew.w, E0.w, aev);

    // dequant partials (scales identical within lane pair), reduce via shfl_xor(1)
    float p0 = (float)ah0 * shE[0] + (float)ax[0] * (sxE[0] * sv.x);
    float p1 = (float)ah1 * shE[1] + (float)ax[1] * (sxE[1] * sv.x);
    float p2 = (float)ah2 * shE[2] + (float)ax[2] * (sxE[2] * sv.x);
    float p3 = (float)ah3 * shE[3] + (float)ax[3] * (sxE[3] * sv.x);
    float p4 = (float)ah4 * shE[4];
    float p5 = (float)ax[4] * (sxE[4] * sv.x);
    float p6 = (float)aev * (seE * sv.y);
    p0 += __shfl_xor(p0, 1); p1 += __shfl_xor(p1, 1);
    p2 += __shfl_xor(p2, 1); p3 += __shfl_xor(p3, 1);
    p4 += __shfl_xor(p4, 1); p5 += __shfl_xor(p5, 1);
    p6 += __shfl_xor(p6, 1);
    p0 += bf0; p1 += bf1; p2 += bf2; p3 += bf3;
    p4 += bhgv; p5 += bmkv; p6 += bev;

    // elementwise (redundant across the lane pair; keeps both lanes' c in sync)
    const float impact = tanh_f(p6) * sigm(p4) * sv.z;
    c = sigm(p1) * c + sigm(p0) * tanh_f(p2) + sigm(p5) * tanh_f(impact);
    const float hn = sigm(p3) * tanh_f(c);

    const int qi = __float2int_rn(hn * 127.0f);  // |h|<1 -> fixed scale 1/127
    if (!half) {
      feat[(size_t)bt * HH + j] = hn;
      hqB[buf ^ 1][j] = (unsigned char)(qi & 0xff);
    }
    __syncthreads();  // hq[buf^1] ready; hq[buf] reads done
    buf ^= 1;
  }
}

// ---------- predictor MLP: one wave per (b,t) row ----------
__global__ __launch_bounds__(256) void pred_f32(
    const float* __restrict__ feat, const float* __restrict__ Wp1,
    const float* __restrict__ bp1, const float* __restrict__ Wp2,
    const float* __restrict__ bp2, float* __restrict__ out0) {
  __shared__ float sh[4][256];
  const int wid = threadIdx.x >> 6, lane = threadIdx.x & 63;
  const int bt = blockIdx.x * 4 + wid;
  const float4 hv = ((const float4*)feat)[(size_t)bt * 64 + lane];
  ((float4*)&sh[wid][0])[lane] = hv;
  float m0 = bp1[2 * lane], m1 = bp1[2 * lane + 1];
  const float2* w2 = (const float2*)Wp1;
#pragma unroll 8
  for (int k = 0; k < 256; ++k) {
    const float hk = sh[wid][k];
    const float2 wv = w2[k * 64 + lane];
    m0 = fmaf(hk, wv.x, m0);
    m1 = fmaf(hk, wv.y, m1);
  }
  const float g0 = 0.5f * m0 * (1.0f + erff(m0 * 0.70710678118f));
  const float g1 = 0.5f * m1 * (1.0f + erff(m1 * 0.70710678118f));
  float acc = g0 * Wp2[2 * lane] + g1 * Wp2[2 * lane + 1];
#pragma unroll
  for (int d = 1; d < 64; d <<= 1) acc += __shfl_xor(acc, d);
  if (lane == 0) out0[bt] = acc + bp2[0];
}

extern "C" void kernel_launch(void* const* d_in, const int* in_sizes, int n_in,
                              void* d_out, int out_size, void* d_ws, size_t ws_size,
                              hipStream_t stream) {
  const float* x = (const float*)d_in[0];
  const float* ev = (const float*)d_in[1];
  const float* td = (const float*)d_in[2];
  const float* Wproj = (const float*)d_in[3];
  const float* bproj = (const float*)d_in[4];
  const float* Wih = (const float*)d_in[5];
  const float* Whh = (const float*)d_in[6];
  const float* blstm = (const float*)d_in[7];
  const float* Wmk = (const float*)d_in[8];
  const float* bmk = (const float*)d_in[9];
  const float* We = (const float*)d_in[10];
  const float* be = (const float*)d_in[11];
  const float* Whg = (const float*)d_in[12];
  const float* bhg = (const float*)d_in[13];
  const float* decay = (const float*)d_in[14];
  const float* Wp1 = (const float*)d_in[15];
  const float* bp1 = (const float*)d_in[16];
  const float* Wp2 = (const float*)d_in[17];
  const float* bp2 = (const float*)d_in[18];

  float* out0 = (float*)d_out;                // predictions [B,T,1]
  float* out1 = out0 + (size_t)BT;            // features    [B,T,H]
  float* out2 = out1 + (size_t)BT * HH;       // tmdo d1     [B,T,64]

  char* w = (char*)d_ws;
  float* Wfold_f = (float*)w; w += (size_t)64 * 1024 * 4;   // 256 KB
  uint* Whh5q = (uint*)w; w += (size_t)1280 * 64 * 4;       // 320 KB
  uint* Xq = (uint*)w; w += (size_t)1280 * 16 * 4;          // 80 KB
  uint* Eq = (uint*)w; w += (size_t)256 * 8 * 4;            // 8 KB
  float* schE = (float*)w; w += 1280 * 4;
  float* sxj = (float*)w; w += 1280 * 4;
  float* sej = (float*)w; w += 256 * 4;
  float* bfold = (float*)w; w += 1024 * 4;
  uint* xq = (uint*)w; w += (size_t)BT * 16 * 4;            // 8 MB
  uint* eq = (uint*)w; w += (size_t)BT * 8 * 4;             // 4 MB
  float4* scl = (float4*)w; w += (size_t)BT * 16;           // 2 MB

  hipLaunchKernelGGL(fold_f32, dim3(256), dim3(256), 0, stream, Wproj, Wih, Wfold_f);
  hipLaunchKernelGGL(bfold_kernel, dim3(4), dim3(256), 0, stream, bproj, Wih, blstm, bfold);
  hipLaunchKernelGGL(quant_h5, dim3(5), dim3(256), 0, stream, Whh, Whg, Whh5q, schE);
  hipLaunchKernelGGL(quant_x, dim3(5), dim3(256), 0, stream, Wfold_f, Wmk, Xq, sxj);
  hipLaunchKernelGGL(quant_e, dim3(1), dim3(256), 0, stream, We, Eq, sej);
  hipLaunchKernelGGL(prep_inputs, dim3(BT / 4), dim3(256), 0, stream,
                     x, ev, td, decay, xq, eq, scl);
  hipLaunchKernelGGL(d1_kernel, dim3(8192), dim3(256), 0, stream, x, out2);

  hipLaunchKernelGGL(scan_i8, dim3(BB), dim3(512), 0, stream,
                     Whh5q, schE, Xq, sxj, Eq, sej, bfold, bhg, bmk, be,
                     xq, eq, scl, out1);

  hipLaunchKernelGGL(pred_f32, dim3(BT / 4), dim3(256), 0, stream,
                     out1, Wp1, bp1, Wp2, bp2, out0);
}